// Round 15
// baseline (946.301 us; speedup 1.0000x reference)
//
#include <hip/hip_runtime.h>
#include <hip/hip_bf16.h>
#include <cmath>

__device__ inline void unpack_bf2(unsigned int u, float& lo, float& hi) {
    union { unsigned int i; float f; } a, b;
    a.i = u << 16; b.i = u & 0xffff0000u;
    lo = a.f; hi = b.f;
}
__device__ inline unsigned short bf16_bits(float x) {
    __hip_bfloat16 v = __float2bfloat16(x);
    return *reinterpret_cast<unsigned short*>(&v);
}

// ---------------------------------------------------------------------------
// Fused BN(+ELU) + GEMM. A[N,K] -> act -> @ [B0|B1] [K,M].
// C != null : write fp32 C[N,M] (pre-layer); if stats_out, also accumulate
//             per-feature sum/sumsq of C into stats_out[0..2*M).
// C == null : cols 0..63 -> xlb bf16, cols 64..127 -> xrb bf16.
// ---------------------------------------------------------------------------
template<int K, int M, int ROWS>
__global__ __launch_bounds__(256)
void bn_gemm_kernel(const float* __restrict__ A, const float* __restrict__ B0,
                    const float* __restrict__ B1, float* __restrict__ C,
                    __hip_bfloat16* __restrict__ xlb, __hip_bfloat16* __restrict__ xrb,
                    const float* __restrict__ stats, const float* __restrict__ g,
                    const float* __restrict__ b, float* __restrict__ stats_out,
                    int N, float invN)
{
    constexpr int TM  = ROWS * M / 512;   // per-thread cols (2 rows per thread)
    constexpr int LDA = K + 4;
    constexpr int MT  = M / TM;
    __shared__ float Bs[K * M];
    __shared__ float As[ROWS * LDA];
    __shared__ float sA[K], sB[K];
    __shared__ float pst[2][4][64];
    if (stats != nullptr && threadIdx.x < K) {
        float m   = stats[threadIdx.x] * invN;
        float var = stats[K + threadIdx.x] * invN - m * m;
        float a   = g[threadIdx.x] * rsqrtf(var + 1e-5f);
        sA[threadIdx.x] = a;
        sB[threadIdx.x] = b[threadIdx.x] - m * a;
    }
    for (int i = threadIdx.x; i < K * M; i += 256) {
        float v;
        if (B1 != nullptr) {
            int k = i / M, m = i - k * M;
            v = (m < M / 2) ? B0[k * (M / 2) + m] : B1[k * (M / 2) + (m - M / 2)];
        } else {
            v = B0[i];
        }
        Bs[i] = v;
    }
    __syncthreads();
    int row0 = blockIdx.x * ROWS;
    for (int i = threadIdx.x; i < ROWS * K; i += 256) {
        int rr = i / K, kk = i - rr * K;
        int r = row0 + rr;
        float v = (r < N) ? A[(size_t)r * K + kk] : 0.f;
        if (stats != nullptr) {
            float t = fmaf(v, sA[kk], sB[kk]);
            v = (t > 0.f) ? t : expm1f(t);
        }
        As[rr * LDA + kk] = v;
    }
    __syncthreads();
    int r0 = (threadIdx.x / MT) * 2;
    int m0 = (threadIdx.x % MT) * TM;
    float acc0[TM], acc1[TM];
    #pragma unroll
    for (int i = 0; i < TM; ++i) { acc0[i] = 0.f; acc1[i] = 0.f; }
    const float* a0p = &As[r0 * LDA];
    const float* a1p = a0p + LDA;
    for (int k = 0; k < K; ++k) {
        float a0 = a0p[k], a1 = a1p[k];
        #pragma unroll
        for (int mm = 0; mm < TM; mm += 4) {
            float4 bv = *(const float4*)&Bs[k * M + m0 + mm];
            acc0[mm + 0] = fmaf(a0, bv.x, acc0[mm + 0]);
            acc0[mm + 1] = fmaf(a0, bv.y, acc0[mm + 1]);
            acc0[mm + 2] = fmaf(a0, bv.z, acc0[mm + 2]);
            acc0[mm + 3] = fmaf(a0, bv.w, acc0[mm + 3]);
            acc1[mm + 0] = fmaf(a1, bv.x, acc1[mm + 0]);
            acc1[mm + 1] = fmaf(a1, bv.y, acc1[mm + 1]);
            acc1[mm + 2] = fmaf(a1, bv.z, acc1[mm + 2]);
            acc1[mm + 3] = fmaf(a1, bv.w, acc1[mm + 3]);
        }
    }
    int rA = row0 + r0, rB = rA + 1;
    if (C != nullptr) {
        #pragma unroll
        for (int mm = 0; mm < TM; mm += 4) {
            if (rA < N)
                *(float4*)&C[(size_t)rA * M + m0 + mm] =
                    make_float4(acc0[mm], acc0[mm+1], acc0[mm+2], acc0[mm+3]);
            if (rB < N)
                *(float4*)&C[(size_t)rB * M + m0 + mm] =
                    make_float4(acc1[mm], acc1[mm+1], acc1[mm+2], acc1[mm+3]);
        }
    } else {
        unsigned int u0[4], u1[4];
        #pragma unroll
        for (int i = 0; i < 4; ++i) {
            u0[i] = (unsigned int)bf16_bits(acc0[2*i]) |
                    ((unsigned int)bf16_bits(acc0[2*i+1]) << 16);
            u1[i] = (unsigned int)bf16_bits(acc1[2*i]) |
                    ((unsigned int)bf16_bits(acc1[2*i+1]) << 16);
        }
        __hip_bfloat16* dst = (m0 < 64) ? xlb : xrb;
        int mo = (m0 < 64) ? m0 : m0 - 64;
        if (rA < N) *(uint4*)(dst + (size_t)rA * 64 + mo) = make_uint4(u0[0],u0[1],u0[2],u0[3]);
        if (rB < N) *(uint4*)(dst + (size_t)rB * 64 + mo) = make_uint4(u1[0],u1[1],u1[2],u1[3]);
    }
    // fused BN-stats of C (pre-layer only; M == 64 there)
    if (stats_out != nullptr) {
        float s[TM], s2[TM];
        #pragma unroll
        for (int i = 0; i < TM; ++i) {
            s[i]  = acc0[i] + acc1[i];
            s2[i] = acc0[i] * acc0[i] + acc1[i] * acc1[i];
        }
        #pragma unroll
        for (int off = MT; off < 64; off <<= 1) {
            #pragma unroll
            for (int i = 0; i < TM; ++i) {
                s[i]  += __shfl_xor(s[i],  off);
                s2[i] += __shfl_xor(s2[i], off);
            }
        }
        int lane = threadIdx.x & 63, wid = threadIdx.x >> 6;
        if (lane < MT) {
            #pragma unroll
            for (int c = 0; c < TM; ++c) {
                pst[0][wid][lane * TM + c] = s[c];
                pst[1][wid][lane * TM + c] = s2[c];
            }
        }
        __syncthreads();
        if (threadIdx.x < 128) {
            int which = threadIdx.x >> 6, f = threadIdx.x & 63;
            __threadfence();
            atomicAdd(&stats_out[which * 64 + f],
                      pst[which][0][f] + pst[which][1][f] +
                      pst[which][2][f] + pst[which][3][f]);
        }
    }
}

// ---------------------------------------------------------------------------
// CSR build: two-level counting sort on PACKED edges (src<<16 | dst).
// col stores byte offsets src*128.
// ---------------------------------------------------------------------------
__global__ __launch_bounds__(256)
void bin_hist_kernel(const int* __restrict__ dsts, int* __restrict__ binCnt, int E)
{
    __shared__ int lh[4][256];
    for (int i = threadIdx.x; i < 1024; i += 256) ((int*)lh)[i] = 0;
    __syncthreads();
    int bank = threadIdx.x & 3;
    for (int e0 = blockIdx.x * 1024 + threadIdx.x * 4; e0 < E; e0 += gridDim.x * 1024) {
        if (e0 + 3 < E) {
            int4 d = *(const int4*)&dsts[e0];
            atomicAdd(&lh[bank][d.x >> 8], 1);
            atomicAdd(&lh[bank][d.y >> 8], 1);
            atomicAdd(&lh[bank][d.z >> 8], 1);
            atomicAdd(&lh[bank][d.w >> 8], 1);
        } else {
            for (int j = 0; j < 4; ++j)
                if (e0 + j < E) atomicAdd(&lh[bank][dsts[e0 + j] >> 8], 1);
        }
    }
    __syncthreads();
    int s = lh[0][threadIdx.x] + lh[1][threadIdx.x] +
            lh[2][threadIdx.x] + lh[3][threadIdx.x];
    if (s > 0) atomicAdd(&binCnt[threadIdx.x], s);
}

__global__ __launch_bounds__(256)
void bin_scan_kernel(const int* __restrict__ binCnt, int* __restrict__ binBase,
                     int* __restrict__ binCursor, int* __restrict__ row_ptr,
                     int* __restrict__ col, int N, int E)
{
    __shared__ int buf[256];
    int v = binCnt[threadIdx.x];
    buf[threadIdx.x] = v;
    __syncthreads();
    for (int off = 1; off < 256; off <<= 1) {
        int t = (threadIdx.x >= off) ? buf[threadIdx.x - off] : 0;
        __syncthreads();
        buf[threadIdx.x] += t;
        __syncthreads();
    }
    int excl = buf[threadIdx.x] - v;
    binBase[threadIdx.x] = excl;
    binCursor[threadIdx.x] = excl;
    // zero the col pad so no path can observe poison
    if (threadIdx.x < 64) col[E + threadIdx.x] = 0;
    if (threadIdx.x == 255) {
        binBase[256] = buf[255];
        row_ptr[N] = E;
    }
}

#define SCHUNK 4096
__global__ __launch_bounds__(256)
void bin_scatter_kernel(const int* __restrict__ srcs, const int* __restrict__ dsts,
                        int* __restrict__ binCursor, unsigned int* __restrict__ binned,
                        int E)
{
    __shared__ unsigned int stg[SCHUNK];
    __shared__ int bcnt[256], bexcl[256], bcur[256], gbase[256], sbuf[256];
    int c0 = blockIdx.x * SCHUNK;
    int n = min(SCHUNK, E - c0);
    bcnt[threadIdx.x] = 0;
    __syncthreads();
    for (int k = 0; k < SCHUNK / 256; ++k) {
        int i = c0 + k * 256 + threadIdx.x;
        if (i < E) atomicAdd(&bcnt[dsts[i] >> 8], 1);
    }
    __syncthreads();
    int v = bcnt[threadIdx.x];
    sbuf[threadIdx.x] = v;
    __syncthreads();
    for (int off = 1; off < 256; off <<= 1) {
        int t = (threadIdx.x >= off) ? sbuf[threadIdx.x - off] : 0;
        __syncthreads();
        sbuf[threadIdx.x] += t;
        __syncthreads();
    }
    bexcl[threadIdx.x] = sbuf[threadIdx.x] - v;
    bcur[threadIdx.x]  = sbuf[threadIdx.x] - v;
    __syncthreads();
    for (int k = 0; k < SCHUNK / 256; ++k) {
        int i = c0 + k * 256 + threadIdx.x;
        if (i < E) {
            unsigned int s = (unsigned int)srcs[i], d = (unsigned int)dsts[i];
            int pos = atomicAdd(&bcur[d >> 8], 1);
            stg[pos] = (s << 16) | d;
        }
    }
    __syncthreads();
    gbase[threadIdx.x] = atomicAdd(&binCursor[threadIdx.x], bcnt[threadIdx.x]);
    __syncthreads();
    for (int i = threadIdx.x; i < n; i += 256) {
        unsigned int p = stg[i];
        int b = (p & 0xFFFFu) >> 8;
        binned[gbase[b] + (i - bexcl[b])] = p;
    }
}

__global__ __launch_bounds__(256)
void bin_finalize_kernel(const unsigned int* __restrict__ binned,
                         const int* __restrict__ binBase,
                         int* __restrict__ row_ptr, int* __restrict__ col, int N)
{
    __shared__ int cnt[256], excl[256], cur[256];
    int b = blockIdx.x;
    int beg = binBase[b], end = binBase[b + 1];
    cnt[threadIdx.x] = 0;
    __syncthreads();
    for (int i = beg + threadIdx.x; i < end; i += 256)
        atomicAdd(&cnt[binned[i] & 255u], 1);
    __syncthreads();
    int v = cnt[threadIdx.x];
    excl[threadIdx.x] = v;
    __syncthreads();
    for (int off = 1; off < 256; off <<= 1) {
        int t = (threadIdx.x >= off) ? excl[threadIdx.x - off] : 0;
        __syncthreads();
        excl[threadIdx.x] += t;
        __syncthreads();
    }
    int ex = excl[threadIdx.x] - v;
    int dstIdx = b * 256 + threadIdx.x;
    if (dstIdx < N) row_ptr[dstIdx] = beg + ex;
    cur[threadIdx.x] = ex;
    __syncthreads();
    for (int i = beg + threadIdx.x; i < end; i += 256) {
        unsigned int p = binned[i];
        int pos = atomicAdd(&cur[p & 255u], 1);
        col[beg + pos] = (int)(p >> 16) << 7;   // byte offset: src * 128
    }
}

// ---------------------------------------------------------------------------
// Node-centric GATv2, R11-proven: grid-stride over nodes (moving contiguous
// window => chip-wide L2 locality), 16 edges/iter with 2x2 prefetch, header
// software-pipelined, register stats accumulators.
// ---------------------------------------------------------------------------
__device__ inline uint4 ldrow(const char* base_h, int offv, int slot) {
    int off = __shfl(offv, slot);
    return *(const uint4*)(base_h + off);
}

__global__ __launch_bounds__(256)
void gat_node_kernel(const int* __restrict__ row_ptr, const int* __restrict__ coloff,
                     const __hip_bfloat16* __restrict__ xlb,
                     const __hip_bfloat16* __restrict__ xrb,
                     const float* __restrict__ att,
                     const float* __restrict__ zin,
                     const float* __restrict__ stats, const float* __restrict__ g,
                     const float* __restrict__ b,
                     float* __restrict__ zout, float* __restrict__ stats_out,
                     int N, float invN)
{
    int lane = threadIdx.x & 63;
    int wid  = threadIdx.x >> 6;
    int eg   = lane >> 3;
    int h    = lane & 7;

    __shared__ float AB[2][64];
    if (threadIdx.x < 64) {
        float m   = stats[threadIdx.x] * invN;
        float var = stats[64 + threadIdx.x] * invN - m * m;
        float a   = g[threadIdx.x] * rsqrtf(var + 1e-5f);
        AB[0][threadIdx.x] = a;
        AB[1][threadIdx.x] = b[threadIdx.x] - m * a;
    }
    __syncthreads();

    float attv[8];
    {
        const float4* a4 = (const float4*)(att + (h << 3));
        float4 a0 = a4[0], a1 = a4[1];
        attv[0]=a0.x; attv[1]=a0.y; attv[2]=a0.z; attv[3]=a0.w;
        attv[4]=a1.x; attv[5]=a1.y; attv[6]=a1.z; attv[7]=a1.w;
    }
    float fs[8], fs2[8];
    #pragma unroll
    for (int c = 0; c < 8; ++c) { fs[c] = 0.f; fs2[c] = 0.f; }

    const char* xh = (const char*)xlb + (h << 4);
    const int stride = gridDim.x * 4;

    int n = blockIdx.x * 4 + wid;
    int beg = 0, end = 0, cv0 = 0;
    if (n < N) {
        beg = row_ptr[n]; end = row_ptr[n + 1];
        int mm = min(lane, end - beg - 1); if (mm < 0) mm = 0;
        cv0 = coloff[beg + mm];
    }
    while (n < N) {
        uint4 xrp = *(const uint4*)((const char*)xrb + (size_t)n * 128 + (h << 4));
        float xr[8];
        unpack_bf2(xrp.x, xr[0], xr[1]);
        unpack_bf2(xrp.y, xr[2], xr[3]);
        unpack_bf2(xrp.z, xr[4], xr[5]);
        unpack_bf2(xrp.w, xr[6], xr[7]);
        float acc[8];
        #pragma unroll
        for (int c = 0; c < 8; ++c) acc[c] = 0.f;
        float den = 0.f;

        for (int gb = beg; gb < end; gb += 64) {
            int cnt = min(64, end - gb);
            int cm1 = cnt - 1;
            int cv = (gb == beg) ? cv0 : coloff[gb + min(lane, cm1)];
            int nck = (cnt + 15) >> 4;
            uint4 pA = ldrow(xh, cv, min(eg, cm1));
            uint4 pB = ldrow(xh, cv, min(eg + 8, cm1));
            for (int c = 0; c < nck; ++c) {
                uint4 nA = pA, nB = pB;
                if (c + 1 < nck) {
                    nA = ldrow(xh, cv, min((c + 1) * 16 + eg,     cm1));
                    nB = ldrow(xh, cv, min((c + 1) * 16 + 8 + eg, cm1));
                }
                int s0 = c * 16 + eg, s1 = s0 + 8;
                {
                    float xl[8];
                    unpack_bf2(pA.x, xl[0], xl[1]);
                    unpack_bf2(pA.y, xl[2], xl[3]);
                    unpack_bf2(pA.z, xl[4], xl[5]);
                    unpack_bf2(pA.w, xl[6], xl[7]);
                    float logit = 0.f;
                    #pragma unroll
                    for (int cc = 0; cc < 8; ++cc) {
                        float sum = xl[cc] + xr[cc];
                        float lr = fmaxf(sum, 0.2f * sum);
                        logit = fmaf(lr, attv[cc], logit);
                    }
                    float ex = (s0 < cnt) ? __expf(logit) : 0.f;
                    #pragma unroll
                    for (int cc = 0; cc < 8; ++cc) acc[cc] = fmaf(ex, xl[cc], acc[cc]);
                    den += ex;
                }
                {
                    float xl[8];
                    unpack_bf2(pB.x, xl[0], xl[1]);
                    unpack_bf2(pB.y, xl[2], xl[3]);
                    unpack_bf2(pB.z, xl[4], xl[5]);
                    unpack_bf2(pB.w, xl[6], xl[7]);
                    float logit = 0.f;
                    #pragma unroll
                    for (int cc = 0; cc < 8; ++cc) {
                        float sum = xl[cc] + xr[cc];
                        float lr = fmaxf(sum, 0.2f * sum);
                        logit = fmaf(lr, attv[cc], logit);
                    }
                    float ex = (s1 < cnt) ? __expf(logit) : 0.f;
                    #pragma unroll
                    for (int cc = 0; cc < 8; ++cc) acc[cc] = fmaf(ex, xl[cc], acc[cc]);
                    den += ex;
                }
                pA = nA; pB = nB;
            }
        }
        int n2 = n + stride;
        int beg2 = 0, end2 = 0;
        if (n2 < N) { beg2 = row_ptr[n2]; end2 = row_ptr[n2 + 1]; }
        float4 hr0, hr1;
        if (eg == 0) {
            const float4* zp = (const float4*)(zin + (size_t)n * 64 + (h << 3));
            hr0 = zp[0]; hr1 = zp[1];
        }
        #pragma unroll
        for (int off = 8; off <= 32; off <<= 1) {
            den += __shfl_xor(den, off);
            #pragma unroll
            for (int c = 0; c < 8; ++c) acc[c] += __shfl_xor(acc[c], off);
        }
        int cv2 = 0;
        if (n2 < N) {
            int mm = min(lane, end2 - beg2 - 1); if (mm < 0) mm = 0;
            cv2 = coloff[beg2 + mm];
        }
        if (eg == 0) {
            float inv = 1.f / (den + 1e-16f);
            float hraw[8] = {hr0.x, hr0.y, hr0.z, hr0.w, hr1.x, hr1.y, hr1.z, hr1.w};
            float v[8];
            #pragma unroll
            for (int c = 0; c < 8; ++c) {
                int f = (h << 3) + c;
                float t = fmaf(hraw[c], AB[0][f], AB[1][f]);
                float hv = (t > 0.f) ? t : expm1f(t);
                v[c] = fmaf(acc[c], inv, hv);
                fs[c] += v[c];
                fs2[c] += v[c] * v[c];
            }
            float4* z4 = (float4*)(zout + (size_t)n * 64 + (h << 3));
            z4[0] = make_float4(v[0], v[1], v[2], v[3]);
            z4[1] = make_float4(v[4], v[5], v[6], v[7]);
        }
        n = n2; beg = beg2; end = end2; cv0 = cv2;
    }
    __shared__ float lstat[2][4][64];
    if (eg == 0) {
        #pragma unroll
        for (int c = 0; c < 8; ++c) {
            lstat[0][wid][(h << 3) + c] = fs[c];
            lstat[1][wid][(h << 3) + c] = fs2[c];
        }
    }
    __syncthreads();
    if (threadIdx.x < 128) {
        int which = threadIdx.x >> 6;
        int f = threadIdx.x & 63;
        float a = lstat[which][0][f] + lstat[which][1][f] +
                  lstat[which][2][f] + lstat[which][3][f];
        __threadfence();
        atomicAdd(&stats_out[which * 64 + f], a);
    }
}

// ---------------------------------------------------------------------------
// MLP head, ILP-restructured: 4 independent acc chains per j-group,
// float4 LDS weight loads. BN+ELU fused on input.
// ---------------------------------------------------------------------------
__device__ inline float elu_f(float t) { return (t > 0.f) ? t : expm1f(t); }

__global__ __launch_bounds__(256)
void mlp_kernel(const float* __restrict__ z, const float* __restrict__ stats,
                const float* __restrict__ g, const float* __restrict__ b,
                const float* __restrict__ W1, const float* __restrict__ B1,
                const float* __restrict__ W2, const float* __restrict__ B2,
                const float* __restrict__ W3, const float* __restrict__ B3,
                const float* __restrict__ W4, const float* __restrict__ B4,
                float* __restrict__ out, int N, float invN)
{
    __shared__ float w1[64 * 48], w2[48 * 32], w3[32 * 16], w4[16 * 2];
    __shared__ float bb1[48], bb2[32], bb3[16], bb4[2];
    __shared__ float sA[64], sB[64];
    for (int i = threadIdx.x; i < 64 * 48; i += 256) w1[i] = W1[i];
    for (int i = threadIdx.x; i < 48 * 32; i += 256) w2[i] = W2[i];
    for (int i = threadIdx.x; i < 32 * 16; i += 256) w3[i] = W3[i];
    for (int i = threadIdx.x; i < 16 * 2;  i += 256) w4[i] = W4[i];
    if (threadIdx.x < 48) bb1[threadIdx.x] = B1[threadIdx.x];
    if (threadIdx.x < 32) bb2[threadIdx.x] = B2[threadIdx.x];
    if (threadIdx.x < 16) bb3[threadIdx.x] = B3[threadIdx.x];
    if (threadIdx.x < 2)  bb4[threadIdx.x] = B4[threadIdx.x];
    if (threadIdx.x >= 64 && threadIdx.x < 128) {
        int f = threadIdx.x - 64;
        float m   = stats[f] * invN;
        float var = stats[64 + f] * invN - m * m;
        float a   = g[f] * rsqrtf(var + 1e-5f);
        sA[f] = a;
        sB[f] = b[f] - m * a;
    }
    __syncthreads();
    int n = blockIdx.x * 256 + threadIdx.x;
    if (n >= N) return;
    float a[64];
    const float4* hp = (const float4*)(z + (size_t)n * 64);
    #pragma unroll
    for (int i = 0; i < 16; ++i) {
        float4 v = hp[i];
        a[4 * i] = v.x; a[4 * i + 1] = v.y; a[4 * i + 2] = v.z; a[4 * i + 3] = v.w;
    }
    #pragma unroll
    for (int k = 0; k < 64; ++k)
        a[k] = elu_f(fmaf(a[k], sA[k], sB[k]));

    float t1[48];
    for (int j = 0; j < 48; j += 4) {
        float c0 = bb1[j], c1 = bb1[j+1], c2 = bb1[j+2], c3 = bb1[j+3];
        #pragma unroll
        for (int k = 0; k < 64; ++k) {
            float4 wv = *(const float4*)&w1[k * 48 + j];
            c0 = fmaf(a[k], wv.x, c0);
            c1 = fmaf(a[k], wv.y, c1);
            c2 = fmaf(a[k], wv.z, c2);
            c3 = fmaf(a[k], wv.w, c3);
        }
        t1[j] = elu_f(c0); t1[j+1] = elu_f(c1); t1[j+2] = elu_f(c2); t1[j+3] = elu_f(c3);
    }
    float t2[32];
    for (int j = 0; j < 32; j += 4) {
        float c0 = bb2[j], c1 = bb2[j+1], c2 = bb2[j+2], c3 = bb2[j+3];
        #pragma unroll
        for (int k = 0; k < 48; ++k) {
            float4 wv = *(const float4*)&w2[k * 32 + j];
            c0 = fmaf(t1[k], wv.x, c0);
            c1 = fmaf(t1[k], wv.y, c1);
            c2 = fmaf(t1[k], wv.z, c2);
            c3 = fmaf(t1[k], wv.w, c3);
        }
        t2[j] = elu_f(c0); t2[j+1] = elu_f(c1); t2[j+2] = elu_f(c2); t2[j+3] = elu_f(c3);
    }
    float t3[16];
    for (int j = 0; j < 16; j += 4) {
        float c0 = bb3[j], c1 = bb3[j+1], c2 = bb3[j+2], c3 = bb3[j+3];
        #pragma unroll
        for (int k = 0; k < 32; ++k) {
            float4 wv = *(const float4*)&w3[k * 16 + j];
            c0 = fmaf(t2[k], wv.x, c0);
            c1 = fmaf(t2[k], wv.y, c1);
            c2 = fmaf(t2[k], wv.z, c2);
            c3 = fmaf(t2[k], wv.w, c3);
        }
        t3[j] = elu_f(c0); t3[j+1] = elu_f(c1); t3[j+2] = elu_f(c2); t3[j+3] = elu_f(c3);
    }
    float o0 = bb4[0], o1 = bb4[1];
    #pragma unroll
    for (int k = 0; k < 16; ++k) {
        o0 += t3[k] * w4[k * 2 + 0];
        o1 += t3[k] * w4[k * 2 + 1];
    }
    out[(size_t)n * 2 + 0] = o0;
    out[(size_t)n * 2 + 1] = o1;
}

// ---------------------------------------------------------------------------
extern "C" void kernel_launch(void* const* d_in, const int* in_sizes, int n_in,
                              void* d_out, int out_size, void* d_ws, size_t ws_size,
                              hipStream_t stream)
{
    const float* x    = (const float*)d_in[0];
    const int*   ei   = (const int*)d_in[1];
    const float* Wpre = (const float*)d_in[2];
    const float* g0   = (const float*)d_in[3];
    const float* b0   = (const float*)d_in[4];

    const int N = in_sizes[0] / 128;
    const int E = in_sizes[1] / 2;
    const float invN = 1.f / (float)N;
    const int NB = (N + 255) >> 8;

    float* ws  = (float*)d_ws;
    float* zA  = ws;                            // N*64 f32
    float* zB  = zA + (size_t)N * 64;           // N*64 f32  (aliased: binned E uint)
    __hip_bfloat16* xlb = (__hip_bfloat16*)(zB + (size_t)N * 64);  // N*64 bf16
    __hip_bfloat16* xrb = xlb + (size_t)N * 64;                    // N*64 bf16
    float* stats   = (float*)(xrb + (size_t)N * 64);  // 5*128
    int*   row_ptr = (int*)(stats + 5 * 128);   // N+4
    int*   col     = row_ptr + N + 4;           // E + 64 pad
    int*   binCnt    = col + E + 64;            // 256
    int*   binBase   = binCnt + 256;            // 257+pad
    int*   binCursor = binBase + 260;           // 256
    unsigned int* binned = (unsigned int*)zB;   // E packed, dead before zB written

    const int* srcs = ei;
    const int* dsts = ei + E;

    // ---- CSR build ----
    hipMemsetAsync(binCnt, 0, 256 * sizeof(int), stream);
    hipMemsetAsync(stats, 0, 5 * 128 * sizeof(float), stream);
    bin_hist_kernel<<<256, 256, 0, stream>>>(dsts, binCnt, E);
    bin_scan_kernel<<<1, 256, 0, stream>>>(binCnt, binBase, binCursor, row_ptr, col, N, E);
    bin_scatter_kernel<<<(E + SCHUNK - 1) / SCHUNK, 256, 0, stream>>>(
        srcs, dsts, binCursor, binned, E);
    bin_finalize_kernel<<<NB, 256, 0, stream>>>(binned, binBase, row_ptr, col, N);

    // ---- pre-layer: zA = x @ Wpre with fused stats0 ----
    bn_gemm_kernel<128, 64, 32><<<(N + 31) / 32, 256, 0, stream>>>(
        x, Wpre, nullptr, zA, nullptr, nullptr, nullptr, nullptr, nullptr,
        stats, N, invN);

    // ---- 4 GATv2 layers ----
    for (int l = 0; l < 4; ++l) {
        const float* Wl  = (const float*)d_in[5 + 5 * l + 0];
        const float* Wr  = (const float*)d_in[5 + 5 * l + 1];
        const float* att = (const float*)d_in[5 + 5 * l + 2];
        const float* gp = (l == 0) ? g0 : (const float*)d_in[5 + 5 * (l - 1) + 3];
        const float* bp = (l == 0) ? b0 : (const float*)d_in[5 + 5 * (l - 1) + 4];
        float* statsp = stats + 128 * l;
        float* zin  = (l & 1) ? zB : zA;
        float* zout = (l & 1) ? zA : zB;

        bn_gemm_kernel<64, 128, 32><<<(N + 31) / 32, 256, 0, stream>>>(
            zin, Wl, Wr, nullptr, xlb, xrb, statsp, gp, bp, nullptr, N, invN);
        gat_node_kernel<<<2048, 256, 0, stream>>>(
            row_ptr, col, xlb, xrb, att, zin, statsp, gp, bp,
            zout, stats + 128 * (l + 1), N, invN);
    }

    // ---- MLP head (BN4 fused) ----
    const float* g4  = (const float*)d_in[23];
    const float* b4  = (const float*)d_in[24];
    const float* Wp1 = (const float*)d_in[25]; const float* bp1 = (const float*)d_in[26];
    const float* Wp2 = (const float*)d_in[27]; const float* bp2 = (const float*)d_in[28];
    const float* Wp3 = (const float*)d_in[29]; const float* bp3 = (const float*)d_in[30];
    const float* Wp4 = (const float*)d_in[31]; const float* bp4 = (const float*)d_in[32];
    mlp_kernel<<<(N + 255) / 256, 256, 0, stream>>>(
        zA, stats + 512, g4, b4, Wp1, bp1, Wp2, bp2, Wp3, bp3, Wp4, bp4,
        (float*)d_out, N, invN);
}

// Round 16
// 771.276 us; speedup vs baseline: 1.2269x; 1.2269x over previous
//
#include <hip/hip_runtime.h>
#include <hip/hip_bf16.h>
#include <cmath>

__device__ inline void unpack_bf2(unsigned int u, float& lo, float& hi) {
    union { unsigned int i; float f; } a, b;
    a.i = u << 16; b.i = u & 0xffff0000u;
    lo = a.f; hi = b.f;
}
__device__ inline unsigned short bf16_bits(float x) {
    __hip_bfloat16 v = __float2bfloat16(x);
    return *reinterpret_cast<unsigned short*>(&v);
}

// ---------------------------------------------------------------------------
// Fused BN(+ELU) + GEMM. A[N,K] -> act -> @ [B0|B1] [K,M].
// C != null : write fp32 C[N,M] (pre-layer); if part != null, also write
//             per-block partial sum/sumsq of C to part[bid*128 .. +127].
// C == null : cols 0..63 -> xlb bf16, cols 64..127 -> xrb bf16.
// ---------------------------------------------------------------------------
template<int K, int M, int ROWS>
__global__ __launch_bounds__(256)
void bn_gemm_kernel(const float* __restrict__ A, const float* __restrict__ B0,
                    const float* __restrict__ B1, float* __restrict__ C,
                    __hip_bfloat16* __restrict__ xlb, __hip_bfloat16* __restrict__ xrb,
                    const float* __restrict__ stats, const float* __restrict__ g,
                    const float* __restrict__ b, float* __restrict__ part,
                    int N, float invN)
{
    constexpr int TM  = ROWS * M / 512;   // per-thread cols (2 rows per thread)
    constexpr int LDA = K + 4;
    constexpr int MT  = M / TM;
    __shared__ float Bs[K * M];
    __shared__ float As[ROWS * LDA];
    __shared__ float sA[K], sB[K];
    __shared__ float pst[2][4][64];
    if (stats != nullptr && threadIdx.x < K) {
        float m   = stats[threadIdx.x] * invN;
        float var = stats[K + threadIdx.x] * invN - m * m;
        float a   = g[threadIdx.x] * rsqrtf(var + 1e-5f);
        sA[threadIdx.x] = a;
        sB[threadIdx.x] = b[threadIdx.x] - m * a;
    }
    for (int i = threadIdx.x; i < K * M; i += 256) {
        float v;
        if (B1 != nullptr) {
            int k = i / M, m = i - k * M;
            v = (m < M / 2) ? B0[k * (M / 2) + m] : B1[k * (M / 2) + (m - M / 2)];
        } else {
            v = B0[i];
        }
        Bs[i] = v;
    }
    __syncthreads();
    int row0 = blockIdx.x * ROWS;
    for (int i = threadIdx.x; i < ROWS * K; i += 256) {
        int rr = i / K, kk = i - rr * K;
        int r = row0 + rr;
        float v = (r < N) ? A[(size_t)r * K + kk] : 0.f;
        if (stats != nullptr) {
            float t = fmaf(v, sA[kk], sB[kk]);
            v = (t > 0.f) ? t : expm1f(t);
        }
        As[rr * LDA + kk] = v;
    }
    __syncthreads();
    int r0 = (threadIdx.x / MT) * 2;
    int m0 = (threadIdx.x % MT) * TM;
    float acc0[TM], acc1[TM];
    #pragma unroll
    for (int i = 0; i < TM; ++i) { acc0[i] = 0.f; acc1[i] = 0.f; }
    const float* a0p = &As[r0 * LDA];
    const float* a1p = a0p + LDA;
    for (int k = 0; k < K; ++k) {
        float a0 = a0p[k], a1 = a1p[k];
        #pragma unroll
        for (int mm = 0; mm < TM; mm += 4) {
            float4 bv = *(const float4*)&Bs[k * M + m0 + mm];
            acc0[mm + 0] = fmaf(a0, bv.x, acc0[mm + 0]);
            acc0[mm + 1] = fmaf(a0, bv.y, acc0[mm + 1]);
            acc0[mm + 2] = fmaf(a0, bv.z, acc0[mm + 2]);
            acc0[mm + 3] = fmaf(a0, bv.w, acc0[mm + 3]);
            acc1[mm + 0] = fmaf(a1, bv.x, acc1[mm + 0]);
            acc1[mm + 1] = fmaf(a1, bv.y, acc1[mm + 1]);
            acc1[mm + 2] = fmaf(a1, bv.z, acc1[mm + 2]);
            acc1[mm + 3] = fmaf(a1, bv.w, acc1[mm + 3]);
        }
    }
    int rA = row0 + r0, rB = rA + 1;
    if (C != nullptr) {
        #pragma unroll
        for (int mm = 0; mm < TM; mm += 4) {
            if (rA < N)
                *(float4*)&C[(size_t)rA * M + m0 + mm] =
                    make_float4(acc0[mm], acc0[mm+1], acc0[mm+2], acc0[mm+3]);
            if (rB < N)
                *(float4*)&C[(size_t)rB * M + m0 + mm] =
                    make_float4(acc1[mm], acc1[mm+1], acc1[mm+2], acc1[mm+3]);
        }
    } else {
        unsigned int u0[4], u1[4];
        #pragma unroll
        for (int i = 0; i < 4; ++i) {
            u0[i] = (unsigned int)bf16_bits(acc0[2*i]) |
                    ((unsigned int)bf16_bits(acc0[2*i+1]) << 16);
            u1[i] = (unsigned int)bf16_bits(acc1[2*i]) |
                    ((unsigned int)bf16_bits(acc1[2*i+1]) << 16);
        }
        __hip_bfloat16* dst = (m0 < 64) ? xlb : xrb;
        int mo = (m0 < 64) ? m0 : m0 - 64;
        if (rA < N) *(uint4*)(dst + (size_t)rA * 64 + mo) = make_uint4(u0[0],u0[1],u0[2],u0[3]);
        if (rB < N) *(uint4*)(dst + (size_t)rB * 64 + mo) = make_uint4(u1[0],u1[1],u1[2],u1[3]);
    }
    // per-block partial BN-stats of C (pre-layer only; M == 64 there)
    if (part != nullptr) {
        float s[TM], s2[TM];
        #pragma unroll
        for (int i = 0; i < TM; ++i) {
            s[i]  = acc0[i] + acc1[i];
            s2[i] = acc0[i] * acc0[i] + acc1[i] * acc1[i];
        }
        #pragma unroll
        for (int off = MT; off < 64; off <<= 1) {
            #pragma unroll
            for (int i = 0; i < TM; ++i) {
                s[i]  += __shfl_xor(s[i],  off);
                s2[i] += __shfl_xor(s2[i], off);
            }
        }
        int lane = threadIdx.x & 63, wid = threadIdx.x >> 6;
        if (lane < MT) {
            #pragma unroll
            for (int c = 0; c < TM; ++c) {
                pst[0][wid][lane * TM + c] = s[c];
                pst[1][wid][lane * TM + c] = s2[c];
            }
        }
        __syncthreads();
        if (threadIdx.x < 128) {
            int which = threadIdx.x >> 6, f = threadIdx.x & 63;
            part[(size_t)blockIdx.x * 128 + threadIdx.x] =
                pst[which][0][f] + pst[which][1][f] +
                pst[which][2][f] + pst[which][3][f];
        }
    }
}

// ---------------------------------------------------------------------------
// Deterministic stats reduce: part[nb][128] -> stats[128].
// ---------------------------------------------------------------------------
__global__ __launch_bounds__(1024)
void stats_reduce_kernel(const float* __restrict__ part, int nb,
                         float* __restrict__ stats)
{
    __shared__ float ls[8][128];
    int f = threadIdx.x & 127;
    int chunk = threadIdx.x >> 7;   // 0..7
    float s = 0.f;
    for (int r = chunk; r < nb; r += 8)
        s += part[(size_t)r * 128 + f];
    ls[chunk][f] = s;
    __syncthreads();
    if (threadIdx.x < 128) {
        float a = 0.f;
        #pragma unroll
        for (int c = 0; c < 8; ++c) a += ls[c][f];
        stats[f] = a;
    }
}

// ---------------------------------------------------------------------------
// CSR build: two-level counting sort on PACKED edges (src<<16 | dst).
// col stores byte offsets src*128.
// ---------------------------------------------------------------------------
__global__ __launch_bounds__(256)
void bin_hist_kernel(const int* __restrict__ dsts, int* __restrict__ binCnt, int E)
{
    __shared__ int lh[4][256];
    for (int i = threadIdx.x; i < 1024; i += 256) ((int*)lh)[i] = 0;
    __syncthreads();
    int bank = threadIdx.x & 3;
    for (int e0 = blockIdx.x * 1024 + threadIdx.x * 4; e0 < E; e0 += gridDim.x * 1024) {
        if (e0 + 3 < E) {
            int4 d = *(const int4*)&dsts[e0];
            atomicAdd(&lh[bank][d.x >> 8], 1);
            atomicAdd(&lh[bank][d.y >> 8], 1);
            atomicAdd(&lh[bank][d.z >> 8], 1);
            atomicAdd(&lh[bank][d.w >> 8], 1);
        } else {
            for (int j = 0; j < 4; ++j)
                if (e0 + j < E) atomicAdd(&lh[bank][dsts[e0 + j] >> 8], 1);
        }
    }
    __syncthreads();
    int s = lh[0][threadIdx.x] + lh[1][threadIdx.x] +
            lh[2][threadIdx.x] + lh[3][threadIdx.x];
    if (s > 0) atomicAdd(&binCnt[threadIdx.x], s);
}

__global__ __launch_bounds__(256)
void bin_scan_kernel(const int* __restrict__ binCnt, int* __restrict__ binBase,
                     int* __restrict__ binCursor, int* __restrict__ row_ptr,
                     int* __restrict__ col, int N, int E)
{
    __shared__ int buf[256];
    int v = binCnt[threadIdx.x];
    buf[threadIdx.x] = v;
    __syncthreads();
    for (int off = 1; off < 256; off <<= 1) {
        int t = (threadIdx.x >= off) ? buf[threadIdx.x - off] : 0;
        __syncthreads();
        buf[threadIdx.x] += t;
        __syncthreads();
    }
    int excl = buf[threadIdx.x] - v;
    binBase[threadIdx.x] = excl;
    binCursor[threadIdx.x] = excl;
    if (threadIdx.x < 64) col[E + threadIdx.x] = 0;
    if (threadIdx.x == 255) {
        binBase[256] = buf[255];
        row_ptr[N] = E;
    }
}

#define SCHUNK 4096
__global__ __launch_bounds__(256)
void bin_scatter_kernel(const int* __restrict__ srcs, const int* __restrict__ dsts,
                        int* __restrict__ binCursor, unsigned int* __restrict__ binned,
                        int E)
{
    __shared__ unsigned int stg[SCHUNK];
    __shared__ int bcnt[256], bexcl[256], bcur[256], gbase[256], sbuf[256];
    int c0 = blockIdx.x * SCHUNK;
    int n = min(SCHUNK, E - c0);
    bcnt[threadIdx.x] = 0;
    __syncthreads();
    for (int k = 0; k < SCHUNK / 256; ++k) {
        int i = c0 + k * 256 + threadIdx.x;
        if (i < E) atomicAdd(&bcnt[dsts[i] >> 8], 1);
    }
    __syncthreads();
    int v = bcnt[threadIdx.x];
    sbuf[threadIdx.x] = v;
    __syncthreads();
    for (int off = 1; off < 256; off <<= 1) {
        int t = (threadIdx.x >= off) ? sbuf[threadIdx.x - off] : 0;
        __syncthreads();
        sbuf[threadIdx.x] += t;
        __syncthreads();
    }
    bexcl[threadIdx.x] = sbuf[threadIdx.x] - v;
    bcur[threadIdx.x]  = sbuf[threadIdx.x] - v;
    __syncthreads();
    for (int k = 0; k < SCHUNK / 256; ++k) {
        int i = c0 + k * 256 + threadIdx.x;
        if (i < E) {
            unsigned int s = (unsigned int)srcs[i], d = (unsigned int)dsts[i];
            int pos = atomicAdd(&bcur[d >> 8], 1);
            stg[pos] = (s << 16) | d;
        }
    }
    __syncthreads();
    gbase[threadIdx.x] = atomicAdd(&binCursor[threadIdx.x], bcnt[threadIdx.x]);
    __syncthreads();
    for (int i = threadIdx.x; i < n; i += 256) {
        unsigned int p = stg[i];
        int b = (p & 0xFFFFu) >> 8;
        binned[gbase[b] + (i - bexcl[b])] = p;
    }
}

__global__ __launch_bounds__(256)
void bin_finalize_kernel(const unsigned int* __restrict__ binned,
                         const int* __restrict__ binBase,
                         int* __restrict__ row_ptr, int* __restrict__ col, int N)
{
    __shared__ int cnt[256], excl[256], cur[256];
    int b = blockIdx.x;
    int beg = binBase[b], end = binBase[b + 1];
    cnt[threadIdx.x] = 0;
    __syncthreads();
    for (int i = beg + threadIdx.x; i < end; i += 256)
        atomicAdd(&cnt[binned[i] & 255u], 1);
    __syncthreads();
    int v = cnt[threadIdx.x];
    excl[threadIdx.x] = v;
    __syncthreads();
    for (int off = 1; off < 256; off <<= 1) {
        int t = (threadIdx.x >= off) ? excl[threadIdx.x - off] : 0;
        __syncthreads();
        excl[threadIdx.x] += t;
        __syncthreads();
    }
    int ex = excl[threadIdx.x] - v;
    int dstIdx = b * 256 + threadIdx.x;
    if (dstIdx < N) row_ptr[dstIdx] = beg + ex;
    cur[threadIdx.x] = ex;
    __syncthreads();
    for (int i = beg + threadIdx.x; i < end; i += 256) {
        unsigned int p = binned[i];
        int pos = atomicAdd(&cur[p & 255u], 1);
        col[beg + pos] = (int)(p >> 16) << 7;   // byte offset: src * 128
    }
}

// ---------------------------------------------------------------------------
// Node-centric GATv2, R11-proven: grid-stride over nodes, 16 edges/iter with
// 2x2 prefetch, header software-pipelined; per-block partial stats (no atomics).
// ---------------------------------------------------------------------------
__device__ inline uint4 ldrow(const char* base_h, int offv, int slot) {
    int off = __shfl(offv, slot);
    return *(const uint4*)(base_h + off);
}

__global__ __launch_bounds__(256)
void gat_node_kernel(const int* __restrict__ row_ptr, const int* __restrict__ coloff,
                     const __hip_bfloat16* __restrict__ xlb,
                     const __hip_bfloat16* __restrict__ xrb,
                     const float* __restrict__ att,
                     const float* __restrict__ zin,
                     const float* __restrict__ stats, const float* __restrict__ g,
                     const float* __restrict__ b,
                     float* __restrict__ zout, float* __restrict__ part,
                     int N, float invN)
{
    int lane = threadIdx.x & 63;
    int wid  = threadIdx.x >> 6;
    int eg   = lane >> 3;
    int h    = lane & 7;

    __shared__ float AB[2][64];
    if (threadIdx.x < 64) {
        float m   = stats[threadIdx.x] * invN;
        float var = stats[64 + threadIdx.x] * invN - m * m;
        float a   = g[threadIdx.x] * rsqrtf(var + 1e-5f);
        AB[0][threadIdx.x] = a;
        AB[1][threadIdx.x] = b[threadIdx.x] - m * a;
    }
    __syncthreads();

    float attv[8];
    {
        const float4* a4 = (const float4*)(att + (h << 3));
        float4 a0 = a4[0], a1 = a4[1];
        attv[0]=a0.x; attv[1]=a0.y; attv[2]=a0.z; attv[3]=a0.w;
        attv[4]=a1.x; attv[5]=a1.y; attv[6]=a1.z; attv[7]=a1.w;
    }
    float fs[8], fs2[8];
    #pragma unroll
    for (int c = 0; c < 8; ++c) { fs[c] = 0.f; fs2[c] = 0.f; }

    const char* xh = (const char*)xlb + (h << 4);
    const int stride = gridDim.x * 4;

    int n = blockIdx.x * 4 + wid;
    int beg = 0, end = 0, cv0 = 0;
    if (n < N) {
        beg = row_ptr[n]; end = row_ptr[n + 1];
        int mm = min(lane, end - beg - 1); if (mm < 0) mm = 0;
        cv0 = coloff[beg + mm];
    }
    while (n < N) {
        uint4 xrp = *(const uint4*)((const char*)xrb + (size_t)n * 128 + (h << 4));
        float xr[8];
        unpack_bf2(xrp.x, xr[0], xr[1]);
        unpack_bf2(xrp.y, xr[2], xr[3]);
        unpack_bf2(xrp.z, xr[4], xr[5]);
        unpack_bf2(xrp.w, xr[6], xr[7]);
        float acc[8];
        #pragma unroll
        for (int c = 0; c < 8; ++c) acc[c] = 0.f;
        float den = 0.f;

        for (int gb = beg; gb < end; gb += 64) {
            int cnt = min(64, end - gb);
            int cm1 = cnt - 1;
            int cv = (gb == beg) ? cv0 : coloff[gb + min(lane, cm1)];
            int nck = (cnt + 15) >> 4;
            uint4 pA = ldrow(xh, cv, min(eg, cm1));
            uint4 pB = ldrow(xh, cv, min(eg + 8, cm1));
            for (int c = 0; c < nck; ++c) {
                uint4 nA = pA, nB = pB;
                if (c + 1 < nck) {
                    nA = ldrow(xh, cv, min((c + 1) * 16 + eg,     cm1));
                    nB = ldrow(xh, cv, min((c + 1) * 16 + 8 + eg, cm1));
                }
                int s0 = c * 16 + eg, s1 = s0 + 8;
                {
                    float xl[8];
                    unpack_bf2(pA.x, xl[0], xl[1]);
                    unpack_bf2(pA.y, xl[2], xl[3]);
                    unpack_bf2(pA.z, xl[4], xl[5]);
                    unpack_bf2(pA.w, xl[6], xl[7]);
                    float logit = 0.f;
                    #pragma unroll
                    for (int cc = 0; cc < 8; ++cc) {
                        float sum = xl[cc] + xr[cc];
                        float lr = fmaxf(sum, 0.2f * sum);
                        logit = fmaf(lr, attv[cc], logit);
                    }
                    float ex = (s0 < cnt) ? __expf(logit) : 0.f;
                    #pragma unroll
                    for (int cc = 0; cc < 8; ++cc) acc[cc] = fmaf(ex, xl[cc], acc[cc]);
                    den += ex;
                }
                {
                    float xl[8];
                    unpack_bf2(pB.x, xl[0], xl[1]);
                    unpack_bf2(pB.y, xl[2], xl[3]);
                    unpack_bf2(pB.z, xl[4], xl[5]);
                    unpack_bf2(pB.w, xl[6], xl[7]);
                    float logit = 0.f;
                    #pragma unroll
                    for (int cc = 0; cc < 8; ++cc) {
                        float sum = xl[cc] + xr[cc];
                        float lr = fmaxf(sum, 0.2f * sum);
                        logit = fmaf(lr, attv[cc], logit);
                    }
                    float ex = (s1 < cnt) ? __expf(logit) : 0.f;
                    #pragma unroll
                    for (int cc = 0; cc < 8; ++cc) acc[cc] = fmaf(ex, xl[cc], acc[cc]);
                    den += ex;
                }
                pA = nA; pB = nB;
            }
        }
        int n2 = n + stride;
        int beg2 = 0, end2 = 0;
        if (n2 < N) { beg2 = row_ptr[n2]; end2 = row_ptr[n2 + 1]; }
        float4 hr0, hr1;
        if (eg == 0) {
            const float4* zp = (const float4*)(zin + (size_t)n * 64 + (h << 3));
            hr0 = zp[0]; hr1 = zp[1];
        }
        #pragma unroll
        for (int off = 8; off <= 32; off <<= 1) {
            den += __shfl_xor(den, off);
            #pragma unroll
            for (int c = 0; c < 8; ++c) acc[c] += __shfl_xor(acc[c], off);
        }
        int cv2 = 0;
        if (n2 < N) {
            int mm = min(lane, end2 - beg2 - 1); if (mm < 0) mm = 0;
            cv2 = coloff[beg2 + mm];
        }
        if (eg == 0) {
            float inv = 1.f / (den + 1e-16f);
            float hraw[8] = {hr0.x, hr0.y, hr0.z, hr0.w, hr1.x, hr1.y, hr1.z, hr1.w};
            float v[8];
            #pragma unroll
            for (int c = 0; c < 8; ++c) {
                int f = (h << 3) + c;
                float t = fmaf(hraw[c], AB[0][f], AB[1][f]);
                float hv = (t > 0.f) ? t : expm1f(t);
                v[c] = fmaf(acc[c], inv, hv);
                fs[c] += v[c];
                fs2[c] += v[c] * v[c];
            }
            float4* z4 = (float4*)(zout + (size_t)n * 64 + (h << 3));
            z4[0] = make_float4(v[0], v[1], v[2], v[3]);
            z4[1] = make_float4(v[4], v[5], v[6], v[7]);
        }
        n = n2; beg = beg2; end = end2; cv0 = cv2;
    }
    __shared__ float lstat[2][4][64];
    if (eg == 0) {
        #pragma unroll
        for (int c = 0; c < 8; ++c) {
            lstat[0][wid][(h << 3) + c] = fs[c];
            lstat[1][wid][(h << 3) + c] = fs2[c];
        }
    }
    __syncthreads();
    if (threadIdx.x < 128) {
        int which = threadIdx.x >> 6;
        int f = threadIdx.x & 63;
        part[(size_t)blockIdx.x * 128 + threadIdx.x] =
            lstat[which][0][f] + lstat[which][1][f] +
            lstat[which][2][f] + lstat[which][3][f];
    }
}

// ---------------------------------------------------------------------------
// MLP head, ILP-restructured: 4 independent acc chains per j-group,
// float4 LDS weight loads. BN+ELU fused on input.
// ---------------------------------------------------------------------------
__device__ inline float elu_f(float t) { return (t > 0.f) ? t : expm1f(t); }

__global__ __launch_bounds__(256)
void mlp_kernel(const float* __restrict__ z, const float* __restrict__ stats,
                const float* __restrict__ g, const float* __restrict__ b,
                const float* __restrict__ W1, const float* __restrict__ B1,
                const float* __restrict__ W2, const float* __restrict__ B2,
                const float* __restrict__ W3, const float* __restrict__ B3,
                const float* __restrict__ W4, const float* __restrict__ B4,
                float* __restrict__ out, int N, float invN)
{
    __shared__ float w1[64 * 48], w2[48 * 32], w3[32 * 16], w4[16 * 2];
    __shared__ float bb1[48], bb2[32], bb3[16], bb4[2];
    __shared__ float sA[64], sB[64];
    for (int i = threadIdx.x; i < 64 * 48; i += 256) w1[i] = W1[i];
    for (int i = threadIdx.x; i < 48 * 32; i += 256) w2[i] = W2[i];
    for (int i = threadIdx.x; i < 32 * 16; i += 256) w3[i] = W3[i];
    for (int i = threadIdx.x; i < 16 * 2;  i += 256) w4[i] = W4[i];
    if (threadIdx.x < 48) bb1[threadIdx.x] = B1[threadIdx.x];
    if (threadIdx.x < 32) bb2[threadIdx.x] = B2[threadIdx.x];
    if (threadIdx.x < 16) bb3[threadIdx.x] = B3[threadIdx.x];
    if (threadIdx.x < 2)  bb4[threadIdx.x] = B4[threadIdx.x];
    if (threadIdx.x >= 64 && threadIdx.x < 128) {
        int f = threadIdx.x - 64;
        float m   = stats[f] * invN;
        float var = stats[64 + f] * invN - m * m;
        float a   = g[f] * rsqrtf(var + 1e-5f);
        sA[f] = a;
        sB[f] = b[f] - m * a;
    }
    __syncthreads();
    int n = blockIdx.x * 256 + threadIdx.x;
    if (n >= N) return;
    float a[64];
    const float4* hp = (const float4*)(z + (size_t)n * 64);
    #pragma unroll
    for (int i = 0; i < 16; ++i) {
        float4 v = hp[i];
        a[4 * i] = v.x; a[4 * i + 1] = v.y; a[4 * i + 2] = v.z; a[4 * i + 3] = v.w;
    }
    #pragma unroll
    for (int k = 0; k < 64; ++k)
        a[k] = elu_f(fmaf(a[k], sA[k], sB[k]));

    float t1[48];
    for (int j = 0; j < 48; j += 4) {
        float c0 = bb1[j], c1 = bb1[j+1], c2 = bb1[j+2], c3 = bb1[j+3];
        #pragma unroll
        for (int k = 0; k < 64; ++k) {
            float4 wv = *(const float4*)&w1[k * 48 + j];
            c0 = fmaf(a[k], wv.x, c0);
            c1 = fmaf(a[k], wv.y, c1);
            c2 = fmaf(a[k], wv.z, c2);
            c3 = fmaf(a[k], wv.w, c3);
        }
        t1[j] = elu_f(c0); t1[j+1] = elu_f(c1); t1[j+2] = elu_f(c2); t1[j+3] = elu_f(c3);
    }
    float t2[32];
    for (int j = 0; j < 32; j += 4) {
        float c0 = bb2[j], c1 = bb2[j+1], c2 = bb2[j+2], c3 = bb2[j+3];
        #pragma unroll
        for (int k = 0; k < 48; ++k) {
            float4 wv = *(const float4*)&w2[k * 32 + j];
            c0 = fmaf(t1[k], wv.x, c0);
            c1 = fmaf(t1[k], wv.y, c1);
            c2 = fmaf(t1[k], wv.z, c2);
            c3 = fmaf(t1[k], wv.w, c3);
        }
        t2[j] = elu_f(c0); t2[j+1] = elu_f(c1); t2[j+2] = elu_f(c2); t2[j+3] = elu_f(c3);
    }
    float t3[16];
    for (int j = 0; j < 16; j += 4) {
        float c0 = bb3[j], c1 = bb3[j+1], c2 = bb3[j+2], c3 = bb3[j+3];
        #pragma unroll
        for (int k = 0; k < 32; ++k) {
            float4 wv = *(const float4*)&w3[k * 16 + j];
            c0 = fmaf(t2[k], wv.x, c0);
            c1 = fmaf(t2[k], wv.y, c1);
            c2 = fmaf(t2[k], wv.z, c2);
            c3 = fmaf(t2[k], wv.w, c3);
        }
        t3[j] = elu_f(c0); t3[j+1] = elu_f(c1); t3[j+2] = elu_f(c2); t3[j+3] = elu_f(c3);
    }
    float o0 = bb4[0], o1 = bb4[1];
    #pragma unroll
    for (int k = 0; k < 16; ++k) {
        o0 += t3[k] * w4[k * 2 + 0];
        o1 += t3[k] * w4[k * 2 + 1];
    }
    out[(size_t)n * 2 + 0] = o0;
    out[(size_t)n * 2 + 1] = o1;
}

// ---------------------------------------------------------------------------
extern "C" void kernel_launch(void* const* d_in, const int* in_sizes, int n_in,
                              void* d_out, int out_size, void* d_ws, size_t ws_size,
                              hipStream_t stream)
{
    const float* x    = (const float*)d_in[0];
    const int*   ei   = (const int*)d_in[1];
    const float* Wpre = (const float*)d_in[2];
    const float* g0   = (const float*)d_in[3];
    const float* b0   = (const float*)d_in[4];

    const int N = in_sizes[0] / 128;
    const int E = in_sizes[1] / 2;
    const float invN = 1.f / (float)N;
    const int NB = (N + 255) >> 8;
    const int GB = (N + 31) / 32;     // gemm grid
    const int GG = 2048;              // gat grid

    float* ws  = (float*)d_ws;
    float* zA  = ws;                            // N*64 f32
    float* zB  = zA + (size_t)N * 64;           // N*64 f32  (aliased: binned E uint)
    __hip_bfloat16* xlb = (__hip_bfloat16*)(zB + (size_t)N * 64);  // N*64 bf16
    __hip_bfloat16* xrb = xlb + (size_t)N * 64;                    // N*64 bf16
    float* stats   = (float*)(xrb + (size_t)N * 64);  // 5*128
    int*   row_ptr = (int*)(stats + 5 * 128);   // N+4
    int*   col     = row_ptr + N + 4;           // E + 64 pad
    int*   binCnt    = col + E + 64;            // 256
    int*   binBase   = binCnt + 256;            // 257+pad
    int*   binCursor = binBase + 260;           // 256
    float* part    = (float*)(binCursor + 256); // max(GB,GG)*128
    unsigned int* binned = (unsigned int*)zB;   // E packed, dead before zB written

    const int* srcs = ei;
    const int* dsts = ei + E;

    // ---- CSR build ----
    hipMemsetAsync(binCnt, 0, 256 * sizeof(int), stream);
    bin_hist_kernel<<<256, 256, 0, stream>>>(dsts, binCnt, E);
    bin_scan_kernel<<<1, 256, 0, stream>>>(binCnt, binBase, binCursor, row_ptr, col, N, E);
    bin_scatter_kernel<<<(E + SCHUNK - 1) / SCHUNK, 256, 0, stream>>>(
        srcs, dsts, binCursor, binned, E);
    bin_finalize_kernel<<<NB, 256, 0, stream>>>(binned, binBase, row_ptr, col, N);

    // ---- pre-layer: zA = x @ Wpre with per-block partial stats ----
    bn_gemm_kernel<128, 64, 32><<<GB, 256, 0, stream>>>(
        x, Wpre, nullptr, zA, nullptr, nullptr, nullptr, nullptr, nullptr,
        part, N, invN);
    stats_reduce_kernel<<<1, 1024, 0, stream>>>(part, GB, stats);

    // ---- 4 GATv2 layers ----
    for (int l = 0; l < 4; ++l) {
        const float* Wl  = (const float*)d_in[5 + 5 * l + 0];
        const float* Wr  = (const float*)d_in[5 + 5 * l + 1];
        const float* att = (const float*)d_in[5 + 5 * l + 2];
        const float* gp = (l == 0) ? g0 : (const float*)d_in[5 + 5 * (l - 1) + 3];
        const float* bp = (l == 0) ? b0 : (const float*)d_in[5 + 5 * (l - 1) + 4];
        float* statsp = stats + 128 * l;
        float* zin  = (l & 1) ? zB : zA;
        float* zout = (l & 1) ? zA : zB;

        bn_gemm_kernel<64, 128, 32><<<GB, 256, 0, stream>>>(
            zin, Wl, Wr, nullptr, xlb, xrb, statsp, gp, bp, nullptr, N, invN);
        gat_node_kernel<<<GG, 256, 0, stream>>>(
            row_ptr, col, xlb, xrb, att, zin, statsp, gp, bp,
            zout, part, N, invN);
        stats_reduce_kernel<<<1, 1024, 0, stream>>>(part, GG, stats + 128 * (l + 1));
    }

    // ---- MLP head (BN4 fused) ----
    const float* g4  = (const float*)d_in[23];
    const float* b4  = (const float*)d_in[24];
    const float* Wp1 = (const float*)d_in[25]; const float* bp1 = (const float*)d_in[26];
    const float* Wp2 = (const float*)d_in[27]; const float* bp2 = (const float*)d_in[28];
    const float* Wp3 = (const float*)d_in[29]; const float* bp3 = (const float*)d_in[30];
    const float* Wp4 = (const float*)d_in[31]; const float* bp4 = (const float*)d_in[32];
    mlp_kernel<<<(N + 255) / 256, 256, 0, stream>>>(
        zA, stats + 512, g4, b4, Wp1, bp1, Wp2, bp2, Wp3, bp3, Wp4, bp4,
        (float*)d_out, N, invN);
}

// Round 17
// 516.968 us; speedup vs baseline: 1.8305x; 1.4919x over previous
//
#include <hip/hip_runtime.h>
#include <hip/hip_bf16.h>
#include <cmath>

__device__ inline void unpack_bf2(unsigned int u, float& lo, float& hi) {
    union { unsigned int i; float f; } a, b;
    a.i = u << 16; b.i = u & 0xffff0000u;
    lo = a.f; hi = b.f;
}
__device__ inline unsigned short bf16_bits(float x) {
    __hip_bfloat16 v = __float2bfloat16(x);
    return *reinterpret_cast<unsigned short*>(&v);
}

// ---------------------------------------------------------------------------
// Fused BN(+ELU) + GEMM. A[N,K] -> act -> @ [B0|B1] [K,M].
// C != null : write fp32 C[N,M] (pre-layer); if part != null, also write
//             per-block partial sum/sumsq of C to part[bid*128 .. +127].
// C == null : cols 0..63 -> xlb bf16, cols 64..127 -> xrb bf16.
// ---------------------------------------------------------------------------
template<int K, int M, int ROWS>
__global__ __launch_bounds__(256)
void bn_gemm_kernel(const float* __restrict__ A, const float* __restrict__ B0,
                    const float* __restrict__ B1, float* __restrict__ C,
                    __hip_bfloat16* __restrict__ xlb, __hip_bfloat16* __restrict__ xrb,
                    const float* __restrict__ stats, const float* __restrict__ g,
                    const float* __restrict__ b, float* __restrict__ part,
                    int N, float invN)
{
    constexpr int TM  = ROWS * M / 512;   // per-thread cols (2 rows per thread)
    constexpr int LDA = K + 4;
    constexpr int MT  = M / TM;
    __shared__ float Bs[K * M];
    __shared__ float As[ROWS * LDA];
    __shared__ float sA[K], sB[K];
    __shared__ float pst[2][4][64];
    if (stats != nullptr && threadIdx.x < K) {
        float m   = stats[threadIdx.x] * invN;
        float var = stats[K + threadIdx.x] * invN - m * m;
        float a   = g[threadIdx.x] * rsqrtf(var + 1e-5f);
        sA[threadIdx.x] = a;
        sB[threadIdx.x] = b[threadIdx.x] - m * a;
    }
    for (int i = threadIdx.x; i < K * M; i += 256) {
        float v;
        if (B1 != nullptr) {
            int k = i / M, m = i - k * M;
            v = (m < M / 2) ? B0[k * (M / 2) + m] : B1[k * (M / 2) + (m - M / 2)];
        } else {
            v = B0[i];
        }
        Bs[i] = v;
    }
    __syncthreads();
    int row0 = blockIdx.x * ROWS;
    for (int i = threadIdx.x; i < ROWS * K; i += 256) {
        int rr = i / K, kk = i - rr * K;
        int r = row0 + rr;
        float v = (r < N) ? A[(size_t)r * K + kk] : 0.f;
        if (stats != nullptr) {
            float t = fmaf(v, sA[kk], sB[kk]);
            v = (t > 0.f) ? t : expm1f(t);
        }
        As[rr * LDA + kk] = v;
    }
    __syncthreads();
    int r0 = (threadIdx.x / MT) * 2;
    int m0 = (threadIdx.x % MT) * TM;
    float acc0[TM], acc1[TM];
    #pragma unroll
    for (int i = 0; i < TM; ++i) { acc0[i] = 0.f; acc1[i] = 0.f; }
    const float* a0p = &As[r0 * LDA];
    const float* a1p = a0p + LDA;
    for (int k = 0; k < K; ++k) {
        float a0 = a0p[k], a1 = a1p[k];
        #pragma unroll
        for (int mm = 0; mm < TM; mm += 4) {
            float4 bv = *(const float4*)&Bs[k * M + m0 + mm];
            acc0[mm + 0] = fmaf(a0, bv.x, acc0[mm + 0]);
            acc0[mm + 1] = fmaf(a0, bv.y, acc0[mm + 1]);
            acc0[mm + 2] = fmaf(a0, bv.z, acc0[mm + 2]);
            acc0[mm + 3] = fmaf(a0, bv.w, acc0[mm + 3]);
            acc1[mm + 0] = fmaf(a1, bv.x, acc1[mm + 0]);
            acc1[mm + 1] = fmaf(a1, bv.y, acc1[mm + 1]);
            acc1[mm + 2] = fmaf(a1, bv.z, acc1[mm + 2]);
            acc1[mm + 3] = fmaf(a1, bv.w, acc1[mm + 3]);
        }
    }
    int rA = row0 + r0, rB = rA + 1;
    if (C != nullptr) {
        #pragma unroll
        for (int mm = 0; mm < TM; mm += 4) {
            if (rA < N)
                *(float4*)&C[(size_t)rA * M + m0 + mm] =
                    make_float4(acc0[mm], acc0[mm+1], acc0[mm+2], acc0[mm+3]);
            if (rB < N)
                *(float4*)&C[(size_t)rB * M + m0 + mm] =
                    make_float4(acc1[mm], acc1[mm+1], acc1[mm+2], acc1[mm+3]);
        }
    } else {
        unsigned int u0[4], u1[4];
        #pragma unroll
        for (int i = 0; i < 4; ++i) {
            u0[i] = (unsigned int)bf16_bits(acc0[2*i]) |
                    ((unsigned int)bf16_bits(acc0[2*i+1]) << 16);
            u1[i] = (unsigned int)bf16_bits(acc1[2*i]) |
                    ((unsigned int)bf16_bits(acc1[2*i+1]) << 16);
        }
        __hip_bfloat16* dst = (m0 < 64) ? xlb : xrb;
        int mo = (m0 < 64) ? m0 : m0 - 64;
        if (rA < N) *(uint4*)(dst + (size_t)rA * 64 + mo) = make_uint4(u0[0],u0[1],u0[2],u0[3]);
        if (rB < N) *(uint4*)(dst + (size_t)rB * 64 + mo) = make_uint4(u1[0],u1[1],u1[2],u1[3]);
    }
    // per-block partial BN-stats of C (pre-layer only; M == 64 there)
    if (part != nullptr) {
        float s[TM], s2[TM];
        #pragma unroll
        for (int i = 0; i < TM; ++i) {
            s[i]  = acc0[i] + acc1[i];
            s2[i] = acc0[i] * acc0[i] + acc1[i] * acc1[i];
        }
        #pragma unroll
        for (int off = MT; off < 64; off <<= 1) {
            #pragma unroll
            for (int i = 0; i < TM; ++i) {
                s[i]  += __shfl_xor(s[i],  off);
                s2[i] += __shfl_xor(s2[i], off);
            }
        }
        int lane = threadIdx.x & 63, wid = threadIdx.x >> 6;
        if (lane < MT) {
            #pragma unroll
            for (int c = 0; c < TM; ++c) {
                pst[0][wid][lane * TM + c] = s[c];
                pst[1][wid][lane * TM + c] = s2[c];
            }
        }
        __syncthreads();
        if (threadIdx.x < 128) {
            int which = threadIdx.x >> 6, f = threadIdx.x & 63;
            part[(size_t)blockIdx.x * 128 + threadIdx.x] =
                pst[which][0][f] + pst[which][1][f] +
                pst[which][2][f] + pst[which][3][f];
        }
    }
}

// ---------------------------------------------------------------------------
// Deterministic two-stage stats reduce.
// Stage 1: 64 blocks, block b sums rows b, b+64, ... of part -> part2[b][128].
// Stage 2: 1 block sums the 64 rows of part2 -> stats[128].
// ---------------------------------------------------------------------------
__global__ __launch_bounds__(128)
void stats_reduce1_kernel(const float* __restrict__ part, int nb,
                          float* __restrict__ part2)
{
    int f = threadIdx.x;
    float s = 0.f;
    for (int r = blockIdx.x; r < nb; r += 64)
        s += part[(size_t)r * 128 + f];
    part2[(size_t)blockIdx.x * 128 + f] = s;
}

__global__ __launch_bounds__(128)
void stats_reduce2_kernel(const float* __restrict__ part2,
                          float* __restrict__ stats)
{
    int f = threadIdx.x;
    float a = 0.f;
    #pragma unroll 8
    for (int r = 0; r < 64; ++r)
        a += part2[(size_t)r * 128 + f];
    stats[f] = a;
}

// ---------------------------------------------------------------------------
// CSR build: two-level counting sort on PACKED edges (src<<16 | dst).
// col stores byte offsets src*128.
// ---------------------------------------------------------------------------
__global__ __launch_bounds__(256)
void bin_hist_kernel(const int* __restrict__ dsts, int* __restrict__ binCnt, int E)
{
    __shared__ int lh[4][256];
    for (int i = threadIdx.x; i < 1024; i += 256) ((int*)lh)[i] = 0;
    __syncthreads();
    int bank = threadIdx.x & 3;
    for (int e0 = blockIdx.x * 1024 + threadIdx.x * 4; e0 < E; e0 += gridDim.x * 1024) {
        if (e0 + 3 < E) {
            int4 d = *(const int4*)&dsts[e0];
            atomicAdd(&lh[bank][d.x >> 8], 1);
            atomicAdd(&lh[bank][d.y >> 8], 1);
            atomicAdd(&lh[bank][d.z >> 8], 1);
            atomicAdd(&lh[bank][d.w >> 8], 1);
        } else {
            for (int j = 0; j < 4; ++j)
                if (e0 + j < E) atomicAdd(&lh[bank][dsts[e0 + j] >> 8], 1);
        }
    }
    __syncthreads();
    int s = lh[0][threadIdx.x] + lh[1][threadIdx.x] +
            lh[2][threadIdx.x] + lh[3][threadIdx.x];
    if (s > 0) atomicAdd(&binCnt[threadIdx.x], s);
}

__global__ __launch_bounds__(256)
void bin_scan_kernel(const int* __restrict__ binCnt, int* __restrict__ binBase,
                     int* __restrict__ binCursor, int* __restrict__ row_ptr,
                     int* __restrict__ col, int N, int E)
{
    __shared__ int buf[256];
    int v = binCnt[threadIdx.x];
    buf[threadIdx.x] = v;
    __syncthreads();
    for (int off = 1; off < 256; off <<= 1) {
        int t = (threadIdx.x >= off) ? buf[threadIdx.x - off] : 0;
        __syncthreads();
        buf[threadIdx.x] += t;
        __syncthreads();
    }
    int excl = buf[threadIdx.x] - v;
    binBase[threadIdx.x] = excl;
    binCursor[threadIdx.x] = excl;
    if (threadIdx.x < 64) col[E + threadIdx.x] = 0;
    if (threadIdx.x == 255) {
        binBase[256] = buf[255];
        row_ptr[N] = E;
    }
}

#define SCHUNK 4096
__global__ __launch_bounds__(256)
void bin_scatter_kernel(const int* __restrict__ srcs, const int* __restrict__ dsts,
                        int* __restrict__ binCursor, unsigned int* __restrict__ binned,
                        int E)
{
    __shared__ unsigned int stg[SCHUNK];
    __shared__ int bcnt[256], bexcl[256], bcur[256], gbase[256], sbuf[256];
    int c0 = blockIdx.x * SCHUNK;
    int n = min(SCHUNK, E - c0);
    bcnt[threadIdx.x] = 0;
    __syncthreads();
    for (int k = 0; k < SCHUNK / 256; ++k) {
        int i = c0 + k * 256 + threadIdx.x;
        if (i < E) atomicAdd(&bcnt[dsts[i] >> 8], 1);
    }
    __syncthreads();
    int v = bcnt[threadIdx.x];
    sbuf[threadIdx.x] = v;
    __syncthreads();
    for (int off = 1; off < 256; off <<= 1) {
        int t = (threadIdx.x >= off) ? sbuf[threadIdx.x - off] : 0;
        __syncthreads();
        sbuf[threadIdx.x] += t;
        __syncthreads();
    }
    bexcl[threadIdx.x] = sbuf[threadIdx.x] - v;
    bcur[threadIdx.x]  = sbuf[threadIdx.x] - v;
    __syncthreads();
    for (int k = 0; k < SCHUNK / 256; ++k) {
        int i = c0 + k * 256 + threadIdx.x;
        if (i < E) {
            unsigned int s = (unsigned int)srcs[i], d = (unsigned int)dsts[i];
            int pos = atomicAdd(&bcur[d >> 8], 1);
            stg[pos] = (s << 16) | d;
        }
    }
    __syncthreads();
    gbase[threadIdx.x] = atomicAdd(&binCursor[threadIdx.x], bcnt[threadIdx.x]);
    __syncthreads();
    for (int i = threadIdx.x; i < n; i += 256) {
        unsigned int p = stg[i];
        int b = (p & 0xFFFFu) >> 8;
        binned[gbase[b] + (i - bexcl[b])] = p;
    }
}

__global__ __launch_bounds__(256)
void bin_finalize_kernel(const unsigned int* __restrict__ binned,
                         const int* __restrict__ binBase,
                         int* __restrict__ row_ptr, int* __restrict__ col, int N)
{
    __shared__ int cnt[256], excl[256], cur[256];
    int b = blockIdx.x;
    int beg = binBase[b], end = binBase[b + 1];
    cnt[threadIdx.x] = 0;
    __syncthreads();
    for (int i = beg + threadIdx.x; i < end; i += 256)
        atomicAdd(&cnt[binned[i] & 255u], 1);
    __syncthreads();
    int v = cnt[threadIdx.x];
    excl[threadIdx.x] = v;
    __syncthreads();
    for (int off = 1; off < 256; off <<= 1) {
        int t = (threadIdx.x >= off) ? excl[threadIdx.x - off] : 0;
        __syncthreads();
        excl[threadIdx.x] += t;
        __syncthreads();
    }
    int ex = excl[threadIdx.x] - v;
    int dstIdx = b * 256 + threadIdx.x;
    if (dstIdx < N) row_ptr[dstIdx] = beg + ex;
    cur[threadIdx.x] = ex;
    __syncthreads();
    for (int i = beg + threadIdx.x; i < end; i += 256) {
        unsigned int p = binned[i];
        int pos = atomicAdd(&cur[p & 255u], 1);
        col[beg + pos] = (int)(p >> 16) << 7;   // byte offset: src * 128
    }
}

// ---------------------------------------------------------------------------
// Node-centric GATv2, R11-proven: grid-stride over nodes, 16 edges/iter with
// 2x2 prefetch, header software-pipelined; per-block partial stats (no atomics).
// ---------------------------------------------------------------------------
__device__ inline uint4 ldrow(const char* base_h, int offv, int slot) {
    int off = __shfl(offv, slot);
    return *(const uint4*)(base_h + off);
}

__global__ __launch_bounds__(256)
void gat_node_kernel(const int* __restrict__ row_ptr, const int* __restrict__ coloff,
                     const __hip_bfloat16* __restrict__ xlb,
                     const __hip_bfloat16* __restrict__ xrb,
                     const float* __restrict__ att,
                     const float* __restrict__ zin,
                     const float* __restrict__ stats, const float* __restrict__ g,
                     const float* __restrict__ b,
                     float* __restrict__ zout, float* __restrict__ part,
                     int N, float invN)
{
    int lane = threadIdx.x & 63;
    int wid  = threadIdx.x >> 6;
    int eg   = lane >> 3;
    int h    = lane & 7;

    __shared__ float AB[2][64];
    if (threadIdx.x < 64) {
        float m   = stats[threadIdx.x] * invN;
        float var = stats[64 + threadIdx.x] * invN - m * m;
        float a   = g[threadIdx.x] * rsqrtf(var + 1e-5f);
        AB[0][threadIdx.x] = a;
        AB[1][threadIdx.x] = b[threadIdx.x] - m * a;
    }
    __syncthreads();

    float attv[8];
    {
        const float4* a4 = (const float4*)(att + (h << 3));
        float4 a0 = a4[0], a1 = a4[1];
        attv[0]=a0.x; attv[1]=a0.y; attv[2]=a0.z; attv[3]=a0.w;
        attv[4]=a1.x; attv[5]=a1.y; attv[6]=a1.z; attv[7]=a1.w;
    }
    float fs[8], fs2[8];
    #pragma unroll
    for (int c = 0; c < 8; ++c) { fs[c] = 0.f; fs2[c] = 0.f; }

    const char* xh = (const char*)xlb + (h << 4);
    const int stride = gridDim.x * 4;

    int n = blockIdx.x * 4 + wid;
    int beg = 0, end = 0, cv0 = 0;
    if (n < N) {
        beg = row_ptr[n]; end = row_ptr[n + 1];
        int mm = min(lane, end - beg - 1); if (mm < 0) mm = 0;
        cv0 = coloff[beg + mm];
    }
    while (n < N) {
        uint4 xrp = *(const uint4*)((const char*)xrb + (size_t)n * 128 + (h << 4));
        float xr[8];
        unpack_bf2(xrp.x, xr[0], xr[1]);
        unpack_bf2(xrp.y, xr[2], xr[3]);
        unpack_bf2(xrp.z, xr[4], xr[5]);
        unpack_bf2(xrp.w, xr[6], xr[7]);
        float acc[8];
        #pragma unroll
        for (int c = 0; c < 8; ++c) acc[c] = 0.f;
        float den = 0.f;

        for (int gb = beg; gb < end; gb += 64) {
            int cnt = min(64, end - gb);
            int cm1 = cnt - 1;
            int cv = (gb == beg) ? cv0 : coloff[gb + min(lane, cm1)];
            int nck = (cnt + 15) >> 4;
            uint4 pA = ldrow(xh, cv, min(eg, cm1));
            uint4 pB = ldrow(xh, cv, min(eg + 8, cm1));
            for (int c = 0; c < nck; ++c) {
                uint4 nA = pA, nB = pB;
                if (c + 1 < nck) {
                    nA = ldrow(xh, cv, min((c + 1) * 16 + eg,     cm1));
                    nB = ldrow(xh, cv, min((c + 1) * 16 + 8 + eg, cm1));
                }
                int s0 = c * 16 + eg, s1 = s0 + 8;
                {
                    float xl[8];
                    unpack_bf2(pA.x, xl[0], xl[1]);
                    unpack_bf2(pA.y, xl[2], xl[3]);
                    unpack_bf2(pA.z, xl[4], xl[5]);
                    unpack_bf2(pA.w, xl[6], xl[7]);
                    float logit = 0.f;
                    #pragma unroll
                    for (int cc = 0; cc < 8; ++cc) {
                        float sum = xl[cc] + xr[cc];
                        float lr = fmaxf(sum, 0.2f * sum);
                        logit = fmaf(lr, attv[cc], logit);
                    }
                    float ex = (s0 < cnt) ? __expf(logit) : 0.f;
                    #pragma unroll
                    for (int cc = 0; cc < 8; ++cc) acc[cc] = fmaf(ex, xl[cc], acc[cc]);
                    den += ex;
                }
                {
                    float xl[8];
                    unpack_bf2(pB.x, xl[0], xl[1]);
                    unpack_bf2(pB.y, xl[2], xl[3]);
                    unpack_bf2(pB.z, xl[4], xl[5]);
                    unpack_bf2(pB.w, xl[6], xl[7]);
                    float logit = 0.f;
                    #pragma unroll
                    for (int cc = 0; cc < 8; ++cc) {
                        float sum = xl[cc] + xr[cc];
                        float lr = fmaxf(sum, 0.2f * sum);
                        logit = fmaf(lr, attv[cc], logit);
                    }
                    float ex = (s1 < cnt) ? __expf(logit) : 0.f;
                    #pragma unroll
                    for (int cc = 0; cc < 8; ++cc) acc[cc] = fmaf(ex, xl[cc], acc[cc]);
                    den += ex;
                }
                pA = nA; pB = nB;
            }
        }
        int n2 = n + stride;
        int beg2 = 0, end2 = 0;
        if (n2 < N) { beg2 = row_ptr[n2]; end2 = row_ptr[n2 + 1]; }
        float4 hr0, hr1;
        if (eg == 0) {
            const float4* zp = (const float4*)(zin + (size_t)n * 64 + (h << 3));
            hr0 = zp[0]; hr1 = zp[1];
        }
        #pragma unroll
        for (int off = 8; off <= 32; off <<= 1) {
            den += __shfl_xor(den, off);
            #pragma unroll
            for (int c = 0; c < 8; ++c) acc[c] += __shfl_xor(acc[c], off);
        }
        int cv2 = 0;
        if (n2 < N) {
            int mm = min(lane, end2 - beg2 - 1); if (mm < 0) mm = 0;
            cv2 = coloff[beg2 + mm];
        }
        if (eg == 0) {
            float inv = 1.f / (den + 1e-16f);
            float hraw[8] = {hr0.x, hr0.y, hr0.z, hr0.w, hr1.x, hr1.y, hr1.z, hr1.w};
            float v[8];
            #pragma unroll
            for (int c = 0; c < 8; ++c) {
                int f = (h << 3) + c;
                float t = fmaf(hraw[c], AB[0][f], AB[1][f]);
                float hv = (t > 0.f) ? t : expm1f(t);
                v[c] = fmaf(acc[c], inv, hv);
                fs[c] += v[c];
                fs2[c] += v[c] * v[c];
            }
            float4* z4 = (float4*)(zout + (size_t)n * 64 + (h << 3));
            z4[0] = make_float4(v[0], v[1], v[2], v[3]);
            z4[1] = make_float4(v[4], v[5], v[6], v[7]);
        }
        n = n2; beg = beg2; end = end2; cv0 = cv2;
    }
    __shared__ float lstat[2][4][64];
    if (eg == 0) {
        #pragma unroll
        for (int c = 0; c < 8; ++c) {
            lstat[0][wid][(h << 3) + c] = fs[c];
            lstat[1][wid][(h << 3) + c] = fs2[c];
        }
    }
    __syncthreads();
    if (threadIdx.x < 128) {
        int which = threadIdx.x >> 6;
        int f = threadIdx.x & 63;
        part[(size_t)blockIdx.x * 128 + threadIdx.x] =
            lstat[which][0][f] + lstat[which][1][f] +
            lstat[which][2][f] + lstat[which][3][f];
    }
}

// ---------------------------------------------------------------------------
// MLP head, ILP-restructured: 4 independent acc chains per j-group,
// float4 LDS weight loads. BN+ELU fused on input.
// ---------------------------------------------------------------------------
__device__ inline float elu_f(float t) { return (t > 0.f) ? t : expm1f(t); }

__global__ __launch_bounds__(256)
void mlp_kernel(const float* __restrict__ z, const float* __restrict__ stats,
                const float* __restrict__ g, const float* __restrict__ b,
                const float* __restrict__ W1, const float* __restrict__ B1,
                const float* __restrict__ W2, const float* __restrict__ B2,
                const float* __restrict__ W3, const float* __restrict__ B3,
                const float* __restrict__ W4, const float* __restrict__ B4,
                float* __restrict__ out, int N, float invN)
{
    __shared__ float w1[64 * 48], w2[48 * 32], w3[32 * 16], w4[16 * 2];
    __shared__ float bb1[48], bb2[32], bb3[16], bb4[2];
    __shared__ float sA[64], sB[64];
    for (int i = threadIdx.x; i < 64 * 48; i += 256) w1[i] = W1[i];
    for (int i = threadIdx.x; i < 48 * 32; i += 256) w2[i] = W2[i];
    for (int i = threadIdx.x; i < 32 * 16; i += 256) w3[i] = W3[i];
    for (int i = threadIdx.x; i < 16 * 2;  i += 256) w4[i] = W4[i];
    if (threadIdx.x < 48) bb1[threadIdx.x] = B1[threadIdx.x];
    if (threadIdx.x < 32) bb2[threadIdx.x] = B2[threadIdx.x];
    if (threadIdx.x < 16) bb3[threadIdx.x] = B3[threadIdx.x];
    if (threadIdx.x < 2)  bb4[threadIdx.x] = B4[threadIdx.x];
    if (threadIdx.x >= 64 && threadIdx.x < 128) {
        int f = threadIdx.x - 64;
        float m   = stats[f] * invN;
        float var = stats[64 + f] * invN - m * m;
        float a   = g[f] * rsqrtf(var + 1e-5f);
        sA[f] = a;
        sB[f] = b[f] - m * a;
    }
    __syncthreads();
    int n = blockIdx.x * 256 + threadIdx.x;
    if (n >= N) return;
    float a[64];
    const float4* hp = (const float4*)(z + (size_t)n * 64);
    #pragma unroll
    for (int i = 0; i < 16; ++i) {
        float4 v = hp[i];
        a[4 * i] = v.x; a[4 * i + 1] = v.y; a[4 * i + 2] = v.z; a[4 * i + 3] = v.w;
    }
    #pragma unroll
    for (int k = 0; k < 64; ++k)
        a[k] = elu_f(fmaf(a[k], sA[k], sB[k]));

    float t1[48];
    for (int j = 0; j < 48; j += 4) {
        float c0 = bb1[j], c1 = bb1[j+1], c2 = bb1[j+2], c3 = bb1[j+3];
        #pragma unroll
        for (int k = 0; k < 64; ++k) {
            float4 wv = *(const float4*)&w1[k * 48 + j];
            c0 = fmaf(a[k], wv.x, c0);
            c1 = fmaf(a[k], wv.y, c1);
            c2 = fmaf(a[k], wv.z, c2);
            c3 = fmaf(a[k], wv.w, c3);
        }
        t1[j] = elu_f(c0); t1[j+1] = elu_f(c1); t1[j+2] = elu_f(c2); t1[j+3] = elu_f(c3);
    }
    float t2[32];
    for (int j = 0; j < 32; j += 4) {
        float c0 = bb2[j], c1 = bb2[j+1], c2 = bb2[j+2], c3 = bb2[j+3];
        #pragma unroll
        for (int k = 0; k < 48; ++k) {
            float4 wv = *(const float4*)&w2[k * 32 + j];
            c0 = fmaf(t1[k], wv.x, c0);
            c1 = fmaf(t1[k], wv.y, c1);
            c2 = fmaf(t1[k], wv.z, c2);
            c3 = fmaf(t1[k], wv.w, c3);
        }
        t2[j] = elu_f(c0); t2[j+1] = elu_f(c1); t2[j+2] = elu_f(c2); t2[j+3] = elu_f(c3);
    }
    float t3[16];
    for (int j = 0; j < 16; j += 4) {
        float c0 = bb3[j], c1 = bb3[j+1], c2 = bb3[j+2], c3 = bb3[j+3];
        #pragma unroll
        for (int k = 0; k < 32; ++k) {
            float4 wv = *(const float4*)&w3[k * 16 + j];
            c0 = fmaf(t2[k], wv.x, c0);
            c1 = fmaf(t2[k], wv.y, c1);
            c2 = fmaf(t2[k], wv.z, c2);
            c3 = fmaf(t2[k], wv.w, c3);
        }
        t3[j] = elu_f(c0); t3[j+1] = elu_f(c1); t3[j+2] = elu_f(c2); t3[j+3] = elu_f(c3);
    }
    float o0 = bb4[0], o1 = bb4[1];
    #pragma unroll
    for (int k = 0; k < 16; ++k) {
        o0 += t3[k] * w4[k * 2 + 0];
        o1 += t3[k] * w4[k * 2 + 1];
    }
    out[(size_t)n * 2 + 0] = o0;
    out[(size_t)n * 2 + 1] = o1;
}

// ---------------------------------------------------------------------------
extern "C" void kernel_launch(void* const* d_in, const int* in_sizes, int n_in,
                              void* d_out, int out_size, void* d_ws, size_t ws_size,
                              hipStream_t stream)
{
    const float* x    = (const float*)d_in[0];
    const int*   ei   = (const int*)d_in[1];
    const float* Wpre = (const float*)d_in[2];
    const float* g0   = (const float*)d_in[3];
    const float* b0   = (const float*)d_in[4];

    const int N = in_sizes[0] / 128;
    const int E = in_sizes[1] / 2;
    const float invN = 1.f / (float)N;
    const int NB = (N + 255) >> 8;
    const int GB = (N + 31) / 32;     // gemm grid
    const int GG = 2048;              // gat grid

    float* ws  = (float*)d_ws;
    float* zA  = ws;                            // N*64 f32
    float* zB  = zA + (size_t)N * 64;           // N*64 f32  (aliased: binned E uint)
    __hip_bfloat16* xlb = (__hip_bfloat16*)(zB + (size_t)N * 64);  // N*64 bf16
    __hip_bfloat16* xrb = xlb + (size_t)N * 64;                    // N*64 bf16
    float* stats   = (float*)(xrb + (size_t)N * 64);  // 5*128
    int*   row_ptr = (int*)(stats + 5 * 128);   // N+4
    int*   col     = row_ptr + N + 4;           // E + 64 pad
    int*   binCnt    = col + E + 64;            // 256
    int*   binBase   = binCnt + 256;            // 257+pad
    int*   binCursor = binBase + 260;           // 256
    float* part    = (float*)(binCursor + 256); // max(GB,GG)*128
    float* part2   = part + (size_t)2048 * 128; // 64*128
    unsigned int* binned = (unsigned int*)zB;   // E packed, dead before zB written

    const int* srcs = ei;
    const int* dsts = ei + E;

    // ---- CSR build ----
    hipMemsetAsync(binCnt, 0, 256 * sizeof(int), stream);
    bin_hist_kernel<<<256, 256, 0, stream>>>(dsts, binCnt, E);
    bin_scan_kernel<<<1, 256, 0, stream>>>(binCnt, binBase, binCursor, row_ptr, col, N, E);
    bin_scatter_kernel<<<(E + SCHUNK - 1) / SCHUNK, 256, 0, stream>>>(
        srcs, dsts, binCursor, binned, E);
    bin_finalize_kernel<<<NB, 256, 0, stream>>>(binned, binBase, row_ptr, col, N);

    // ---- pre-layer: zA = x @ Wpre with per-block partial stats ----
    bn_gemm_kernel<128, 64, 32><<<GB, 256, 0, stream>>>(
        x, Wpre, nullptr, zA, nullptr, nullptr, nullptr, nullptr, nullptr,
        part, N, invN);
    stats_reduce1_kernel<<<64, 128, 0, stream>>>(part, GB, part2);
    stats_reduce2_kernel<<<1, 128, 0, stream>>>(part2, stats);

    // ---- 4 GATv2 layers ----
    for (int l = 0; l < 4; ++l) {
        const float* Wl  = (const float*)d_in[5 + 5 * l + 0];
        const float* Wr  = (const float*)d_in[5 + 5 * l + 1];
        const float* att = (const float*)d_in[5 + 5 * l + 2];
        const float* gp = (l == 0) ? g0 : (const float*)d_in[5 + 5 * (l - 1) + 3];
        const float* bp = (l == 0) ? b0 : (const float*)d_in[5 + 5 * (l - 1) + 4];
        float* statsp = stats + 128 * l;
        float* zin  = (l & 1) ? zB : zA;
        float* zout = (l & 1) ? zA : zB;

        bn_gemm_kernel<64, 128, 32><<<GB, 256, 0, stream>>>(
            zin, Wl, Wr, nullptr, xlb, xrb, statsp, gp, bp, nullptr, N, invN);
        gat_node_kernel<<<GG, 256, 0, stream>>>(
            row_ptr, col, xlb, xrb, att, zin, statsp, gp, bp,
            zout, part, N, invN);
        stats_reduce1_kernel<<<64, 128, 0, stream>>>(part, GG, part2);
        stats_reduce2_kernel<<<1, 128, 0, stream>>>(part2, stats + 128 * (l + 1));
    }

    // ---- MLP head (BN4 fused) ----
    const float* g4  = (const float*)d_in[23];
    const float* b4  = (const float*)d_in[24];
    const float* Wp1 = (const float*)d_in[25]; const float* bp1 = (const float*)d_in[26];
    const float* Wp2 = (const float*)d_in[27]; const float* bp2 = (const float*)d_in[28];
    const float* Wp3 = (const float*)d_in[29]; const float* bp3 = (const float*)d_in[30];
    const float* Wp4 = (const float*)d_in[31]; const float* bp4 = (const float*)d_in[32];
    mlp_kernel<<<(N + 255) / 256, 256, 0, stream>>>(
        zA, stats + 512, g4, b4, Wp1, bp1, Wp2, bp2, Wp3, bp3, Wp4, bp4,
        (float*)d_out, N, invN);
}